// Round 6
// baseline (6755.639 us; speedup 1.0000x reference)
//
#include <hip/hip_runtime.h>
#include <math.h>

#define N_ROWS   16384
#define DIM      512
#define DQV      128          // DIM/4 float4s per row
#define K_CODES  8192
#define NSPLIT   2            // code-range split (grid = 128 row tiles * 2 = 256)
#define KHALF    (K_CODES / NSPLIT)
#define BM       128          // rows per block (16 per ty-group)
#define BK       512          // codes per strip
#define BD       8            // d-chunk per tile
#define DCS      (DIM / BD)   // 64 d-chunks
#define NSTRIP   (KHALF / BK) // 8 strips per half
#define THREADS  256
#define EPI_BM   64

#define OUT_LOSS 8388608
#define OUT_PERP 8388609
#define OUT_IDX  8388610

// workspace layout (bytes)
#define WS_XX    0            // 16384 f32
#define WS_BV0   65536        // 16384 f32
#define WS_BI0   131072       // 16384 i32
#define WS_BV1   196608       // 16384 f32
#define WS_BI1   262144       // 16384 i32
#define WS_LOSS  327680       // double
#define WS_MAXI  327688       // int

__global__ void init_ws(double* ws_loss, int* ws_maxidx) {
    *ws_loss = 0.0;
    *ws_maxidx = 0;
}

// ---- numpy pairwise-sum emulation of xx[n] = np.sum(flat**2, axis=1) ----
__device__ __forceinline__ float p128_sq(const float4* p) {
    float4 q0 = p[0], q1 = p[1];
    float r0 = __fmul_rn(q0.x, q0.x), r1 = __fmul_rn(q0.y, q0.y);
    float r2 = __fmul_rn(q0.z, q0.z), r3 = __fmul_rn(q0.w, q0.w);
    float r4 = __fmul_rn(q1.x, q1.x), r5 = __fmul_rn(q1.y, q1.y);
    float r6 = __fmul_rn(q1.z, q1.z), r7 = __fmul_rn(q1.w, q1.w);
    #pragma unroll
    for (int t = 1; t < 16; ++t) {
        q0 = p[2 * t]; q1 = p[2 * t + 1];
        r0 = __fadd_rn(r0, __fmul_rn(q0.x, q0.x));
        r1 = __fadd_rn(r1, __fmul_rn(q0.y, q0.y));
        r2 = __fadd_rn(r2, __fmul_rn(q0.z, q0.z));
        r3 = __fadd_rn(r3, __fmul_rn(q0.w, q0.w));
        r4 = __fadd_rn(r4, __fmul_rn(q1.x, q1.x));
        r5 = __fadd_rn(r5, __fmul_rn(q1.y, q1.y));
        r6 = __fadd_rn(r6, __fmul_rn(q1.z, q1.z));
        r7 = __fadd_rn(r7, __fmul_rn(q1.w, q1.w));
    }
    return __fadd_rn(__fadd_rn(__fadd_rn(r0, r1), __fadd_rn(r2, r3)),
                     __fadd_rn(__fadd_rn(r4, r5), __fadd_rn(r6, r7)));
}

__global__ __launch_bounds__(256) void xx_kernel(const float4* __restrict__ x4,
                                                 float* __restrict__ xx) {
    int row = blockIdx.x * 256 + threadIdx.x;
    const float4* p = x4 + (size_t)row * DQV;
    float a = p128_sq(p);
    float b = p128_sq(p + 32);
    float c = p128_sq(p + 64);
    float d = p128_sq(p + 96);
    xx[row] = __fadd_rn(__fadd_rn(a, b), __fadd_rn(c, d));
}

// 16x16 micro-tile, waves-per-EU = 1: unlocks the upper half of the unified
// 512-VGPR file so acc[16][16] (256 regs) + staging lives in registers.
// Round 5 showed plain __launch_bounds__ caps at 256 VGPR -> 9.7 GB spill.
// Occupancy is 1 wave/SIMD in every measured config anyway; the design goal
// is VALU saturation by a single wave (512 VALU cyc vs 384 LDS cyc per dd).
__global__ __launch_bounds__(THREADS, 1) void vq_main(const float* __restrict__ x,
                                                      const float* __restrict__ emb,
                                                      const float* __restrict__ xx,
                                                      float* __restrict__ bestval,
                                                      int* __restrict__ bestidx,
                                                      float* __restrict__ bestval1,
                                                      int* __restrict__ bestidx1) {
    // LDS: Et 2*16K + Xt 2*4K + redv 16K + redi 16K = 72 KB (1 block/CU)
    __shared__ float Et[2][BD * BK];    // E tile [dd][code], double-buffered
    __shared__ float Xt[2][BD * BM];    // X tile [dd][row], double-buffered
    __shared__ float redv[BM * 32];     // running per-(row,tx) best value
    __shared__ int   redi[BM * 32];     // running per-(row,tx) best index

    const int tid = threadIdx.x;
    const int tx  = tid & 31;             // code group
    const int ty  = tid >> 5;             // row group 0..7 (16 rows each)
    const int rt  = blockIdx.x >> 1;      // row tile
    const int h   = blockIdx.x & 1;       // code half
    const int r0  = rt * BM;
    const int kb  = h * KHALF;

    const float4* x4   = (const float4*)x;
    const float4* emb4 = (const float4*)emb;

    const int c0 = tid;                   // staging code ids within strip
    const int c1 = tid + 256;
    const int xr    = tid >> 1;           // staging row 0..127
    const int xpart = tid & 1;            // which float4 of the d-chunk

    // init running best (ownership mapping: no barrier needed)
    #pragma unroll
    for (int i = 0; i < 16; ++i) {
        int base = (16 * ty + i) * 32 + tx;
        redv[base] = 3.402823466e38f;
        redi[base] = 0;
    }

    float4 pe0, pe1, pe2, pe3, px;

    // prefetch (strip 0, dc 0)
    pe0 = emb4[(size_t)(kb + c0) * DQV + 0];
    pe1 = emb4[(size_t)(kb + c0) * DQV + 1];
    pe2 = emb4[(size_t)(kb + c1) * DQV + 0];
    pe3 = emb4[(size_t)(kb + c1) * DQV + 1];
    px  = x4[(size_t)(r0 + xr) * DQV + xpart];

    for (int kc = 0; kc < NSTRIP; ++kc) {
        const int k0 = kb + kc * BK;

        float acc[16][16];
        #pragma unroll
        for (int i = 0; i < 16; ++i)
            #pragma unroll
            for (int j = 0; j < 16; ++j) acc[i][j] = 0.0f;

        __syncthreads();   // prior strip finished all reads of buf0
        {
            Et[0][0 * BK + c0] = pe0.x; Et[0][1 * BK + c0] = pe0.y;
            Et[0][2 * BK + c0] = pe0.z; Et[0][3 * BK + c0] = pe0.w;
            Et[0][4 * BK + c0] = pe1.x; Et[0][5 * BK + c0] = pe1.y;
            Et[0][6 * BK + c0] = pe1.z; Et[0][7 * BK + c0] = pe1.w;
            Et[0][0 * BK + c1] = pe2.x; Et[0][1 * BK + c1] = pe2.y;
            Et[0][2 * BK + c1] = pe2.z; Et[0][3 * BK + c1] = pe2.w;
            Et[0][4 * BK + c1] = pe3.x; Et[0][5 * BK + c1] = pe3.y;
            Et[0][6 * BK + c1] = pe3.z; Et[0][7 * BK + c1] = pe3.w;
            int db = 4 * xpart;
            Xt[0][(db + 0) * BM + xr] = px.x;
            Xt[0][(db + 1) * BM + xr] = px.y;
            Xt[0][(db + 2) * BM + xr] = px.z;
            Xt[0][(db + 3) * BM + xr] = px.w;
        }

        for (int dc = 0; dc < DCS; ++dc) {
            const int buf = dc & 1;
            __syncthreads();   // buf ready; other buf's readers done

            // prefetch next tile (next dc, or next strip's dc=0)
            {
                int nk0, ndq;
                if (dc < DCS - 1) { nk0 = k0; ndq = 2 * (dc + 1); }
                else { nk0 = (kc < NSTRIP - 1) ? k0 + BK : kb; ndq = 0; }
                pe0 = emb4[(size_t)(nk0 + c0) * DQV + ndq];
                pe1 = emb4[(size_t)(nk0 + c0) * DQV + ndq + 1];
                pe2 = emb4[(size_t)(nk0 + c1) * DQV + ndq];
                pe3 = emb4[(size_t)(nk0 + c1) * DQV + ndq + 1];
                px  = x4[(size_t)(r0 + xr) * DQV + ndq + xpart];
            }

            // k-sequential fp32 FMA chain per (row,code) — bit-matches BLAS GEBP
            #pragma unroll
            for (int dd = 0; dd < BD; ++dd) {
                const float* xp = &Xt[buf][dd * BM + 16 * ty];
                float4 xa = *(const float4*)(xp);
                float4 xb = *(const float4*)(xp + 4);
                float4 xc = *(const float4*)(xp + 8);
                float4 xd = *(const float4*)(xp + 12);
                const float* ep = &Et[buf][dd * BK + 4 * tx];
                float4 e0 = *(const float4*)(ep);
                float4 e1 = *(const float4*)(ep + 128);
                float4 e2 = *(const float4*)(ep + 256);
                float4 e3 = *(const float4*)(ep + 384);
                float xv[16] = {xa.x, xa.y, xa.z, xa.w, xb.x, xb.y, xb.z, xb.w,
                                xc.x, xc.y, xc.z, xc.w, xd.x, xd.y, xd.z, xd.w};
                float ev[16] = {e0.x, e0.y, e0.z, e0.w, e1.x, e1.y, e1.z, e1.w,
                                e2.x, e2.y, e2.z, e2.w, e3.x, e3.y, e3.z, e3.w};
                #pragma unroll
                for (int i = 0; i < 16; ++i)
                    #pragma unroll
                    for (int j = 0; j < 16; ++j)
                        acc[i][j] = __fmaf_rn(xv[i], ev[j], acc[i][j]);
            }

            // store next tile into the other buffer
            if (dc < DCS - 1) {
                const int nb = buf ^ 1;
                Et[nb][0 * BK + c0] = pe0.x; Et[nb][1 * BK + c0] = pe0.y;
                Et[nb][2 * BK + c0] = pe0.z; Et[nb][3 * BK + c0] = pe0.w;
                Et[nb][4 * BK + c0] = pe1.x; Et[nb][5 * BK + c0] = pe1.y;
                Et[nb][6 * BK + c0] = pe1.z; Et[nb][7 * BK + c0] = pe1.w;
                Et[nb][0 * BK + c1] = pe2.x; Et[nb][1 * BK + c1] = pe2.y;
                Et[nb][2 * BK + c1] = pe2.z; Et[nb][3 * BK + c1] = pe2.w;
                Et[nb][4 * BK + c1] = pe3.x; Et[nb][5 * BK + c1] = pe3.y;
                Et[nb][6 * BK + c1] = pe3.z; Et[nb][7 * BK + c1] = pe3.w;
                int db = 4 * xpart;
                Xt[nb][(db + 0) * BM + xr] = px.x;
                Xt[nb][(db + 1) * BM + xr] = px.y;
                Xt[nb][(db + 2) * BM + xr] = px.z;
                Xt[nb][(db + 3) * BM + xr] = px.w;
            }
        }

        // strip epilogue: s = fl(xx - 2*dot); merge into LDS running best.
        // Codes visited ascending; strict < keeps lowest code per fp32 ulp-bin
        // = numpy first-min.
        #pragma unroll
        for (int i = 0; i < 16; ++i) {
            int row = 16 * ty + i;
            float xr_n = xx[r0 + row];          // L1-hot reload (saves 16 VGPRs)
            int base = row * 32 + tx;
            float curv = redv[base];
            int   curi = redi[base];
            #pragma unroll
            for (int j = 0; j < 4; ++j) {
                #pragma unroll
                for (int l = 0; l < 4; ++l) {
                    float s = __fmaf_rn(-2.0f, acc[i][4 * j + l], xr_n);
                    int code = k0 + 128 * j + 4 * tx + l;
                    if (s < curv) { curv = s; curi = code; }
                }
            }
            redv[base] = curv;
            redi[base] = curi;
        }
    }

    // ---- cross-thread argmin reduction ----
    __syncthreads();
    if (tid < BM) {
        int row = tid;
        float v  = redv[row * 32];
        int  idx = redi[row * 32];
        for (int t = 1; t < 32; ++t) {
            float vv = redv[row * 32 + t];
            int   ii = redi[row * 32 + t];
            if (vv < v || (vv == v && ii < idx)) { v = vv; idx = ii; }
        }
        if (h == 0) { bestval[r0 + row]  = v; bestidx[r0 + row]  = idx; }
        else        { bestval1[r0 + row] = v; bestidx1[r0 + row] = idx; }
    }
}

// merge halves + gather + straight-through + loss
__global__ __launch_bounds__(THREADS) void vq_epi(const float* __restrict__ x,
                                                  const float* __restrict__ emb,
                                                  const float* __restrict__ bv0,
                                                  const int* __restrict__ bi0,
                                                  const float* __restrict__ bv1,
                                                  const int* __restrict__ bi1,
                                                  float* __restrict__ out,
                                                  double* __restrict__ ws_loss,
                                                  int* __restrict__ ws_maxidx) {
    __shared__ int idxRow[EPI_BM];
    const int tid = threadIdx.x;
    const int r0  = blockIdx.x * EPI_BM;
    const float4* x4   = (const float4*)x;
    const float4* emb4 = (const float4*)emb;
    float4*       out4 = (float4*)out;

    if (tid < EPI_BM) {
        int row = r0 + tid;
        float v0 = bv0[row]; int i0 = bi0[row];
        float v1 = bv1[row]; int i1 = bi1[row];
        // half0 codes all < half1 codes: tie (v1==v0) keeps i0 = numpy first-min
        int idx = (v1 < v0) ? i1 : i0;
        idxRow[tid] = idx;
        out[OUT_IDX + row] = (float)idx;
        atomicMax(ws_maxidx, idx);
    }
    __syncthreads();

    double lsum = 0.0;
    for (int i = tid; i < EPI_BM * DQV; i += THREADS) {
        int row = i >> 7, dq = i & 127;
        int ki  = idxRow[row];
        float4 q  = emb4[(size_t)ki * DQV + dq];
        float4 xv = x4[(size_t)(r0 + row) * DQV + dq];
        float d0 = q.x - xv.x, d1 = q.y - xv.y, d2 = q.z - xv.z, d3 = q.w - xv.w;
        lsum += (double)d0 * (double)d0 + (double)d1 * (double)d1
              + (double)d2 * (double)d2 + (double)d3 * (double)d3;
        float4 o;
        o.x = xv.x + d0; o.y = xv.y + d1; o.z = xv.z + d2; o.w = xv.w + d3;
        out4[(size_t)(r0 + row) * DQV + dq] = o;
    }
    #pragma unroll
    for (int off = 32; off > 0; off >>= 1) lsum += __shfl_down(lsum, off);
    if ((tid & 63) == 0) atomicAdd(ws_loss, lsum);
}

__global__ void vq_final(const double* __restrict__ ws_loss,
                         const int* __restrict__ ws_maxidx,
                         float* __restrict__ out) {
    if (threadIdx.x == 0) {
        double mean = *ws_loss / (double)((size_t)N_ROWS * DIM);
        out[OUT_LOSS] = (float)(1.25 * mean);   // q_latent + 0.25*e_latent
        double L   = (double)(*ws_maxidx + 1);
        double avg = 1.0 / L;
        out[OUT_PERP] = (float)exp(-avg * log(avg + 1e-10));
    }
}

extern "C" void kernel_launch(void* const* d_in, const int* in_sizes, int n_in,
                              void* d_out, int out_size, void* d_ws, size_t ws_size,
                              hipStream_t stream) {
    const float* x   = (const float*)d_in[0];
    const float* emb = (const float*)d_in[1];
    float* out = (float*)d_out;

    char* ws = (char*)d_ws;
    float*  xx        = (float*)(ws + WS_XX);
    float*  bv0       = (float*)(ws + WS_BV0);
    int*    bi0       = (int*)  (ws + WS_BI0);
    float*  bv1       = (float*)(ws + WS_BV1);
    int*    bi1       = (int*)  (ws + WS_BI1);
    double* ws_loss   = (double*)(ws + WS_LOSS);
    int*    ws_maxidx = (int*)  (ws + WS_MAXI);

    hipLaunchKernelGGL(init_ws, dim3(1), dim3(1), 0, stream, ws_loss, ws_maxidx);
    hipLaunchKernelGGL(xx_kernel, dim3(N_ROWS / 256), dim3(256), 0, stream,
                       (const float4*)x, xx);
    hipLaunchKernelGGL(vq_main, dim3((N_ROWS / BM) * NSPLIT), dim3(THREADS), 0, stream,
                       x, emb, xx, bv0, bi0, bv1, bi1);
    hipLaunchKernelGGL(vq_epi, dim3(N_ROWS / EPI_BM), dim3(THREADS), 0, stream,
                       x, emb, bv0, bi0, bv1, bi1, out, ws_loss, ws_maxidx);
    hipLaunchKernelGGL(vq_final, dim3(1), dim3(64), 0, stream,
                       ws_loss, ws_maxidx, out);
}

// Round 7
// 1858.670 us; speedup vs baseline: 3.6347x; 3.6347x over previous
//
#include <hip/hip_runtime.h>
#include <math.h>

#define N_ROWS   16384
#define DIM      512
#define DQV      128          // DIM/4 float4s per row
#define K_CODES  8192
#define NSPLIT   2
#define KHALF    (K_CODES / NSPLIT)
#define BM       128          // rows per block = 8 waves x 16 rows
#define BK       512          // codes per strip
#define BD       8            // d-chunk per tile
#define DCS      (DIM / BD)   // 64 d-chunks
#define NSTRIP   (KHALF / BK) // 8 strips per half
#define THREADS  512
#define EPI_BM   64

#define OUT_LOSS 8388608
#define OUT_PERP 8388609
#define OUT_IDX  8388610

// workspace layout (bytes)
#define WS_XX    0            // 16384 f32
#define WS_BV0   65536        // 16384 f32
#define WS_BI0   131072       // 16384 i32
#define WS_BV1   196608       // 16384 f32
#define WS_BI1   262144       // 16384 i32
#define WS_LOSS  327680       // double
#define WS_MAXI  327688       // int

__global__ void init_ws(double* ws_loss, int* ws_maxidx) {
    *ws_loss = 0.0;
    *ws_maxidx = 0;
}

// ---- numpy pairwise-sum emulation of xx[n] = np.sum(flat**2, axis=1) ----
__device__ __forceinline__ float p128_sq(const float4* p) {
    float4 q0 = p[0], q1 = p[1];
    float r0 = __fmul_rn(q0.x, q0.x), r1 = __fmul_rn(q0.y, q0.y);
    float r2 = __fmul_rn(q0.z, q0.z), r3 = __fmul_rn(q0.w, q0.w);
    float r4 = __fmul_rn(q1.x, q1.x), r5 = __fmul_rn(q1.y, q1.y);
    float r6 = __fmul_rn(q1.z, q1.z), r7 = __fmul_rn(q1.w, q1.w);
    #pragma unroll
    for (int t = 1; t < 16; ++t) {
        q0 = p[2 * t]; q1 = p[2 * t + 1];
        r0 = __fadd_rn(r0, __fmul_rn(q0.x, q0.x));
        r1 = __fadd_rn(r1, __fmul_rn(q0.y, q0.y));
        r2 = __fadd_rn(r2, __fmul_rn(q0.z, q0.z));
        r3 = __fadd_rn(r3, __fmul_rn(q0.w, q0.w));
        r4 = __fadd_rn(r4, __fmul_rn(q1.x, q1.x));
        r5 = __fadd_rn(r5, __fmul_rn(q1.y, q1.y));
        r6 = __fadd_rn(r6, __fmul_rn(q1.z, q1.z));
        r7 = __fadd_rn(r7, __fmul_rn(q1.w, q1.w));
    }
    return __fadd_rn(__fadd_rn(__fadd_rn(r0, r1), __fadd_rn(r2, r3)),
                     __fadd_rn(__fadd_rn(r4, r5), __fadd_rn(r6, r7)));
}

__global__ __launch_bounds__(256) void xx_kernel(const float4* __restrict__ x4,
                                                 float* __restrict__ xx) {
    int row = blockIdx.x * 256 + threadIdx.x;
    const float4* p = x4 + (size_t)row * DQV;
    float a = p128_sq(p);
    float b = p128_sq(p + 32);
    float c = p128_sq(p + 64);
    float d = p128_sq(p + 96);
    xx[row] = __fadd_rn(__fadd_rn(a, b), __fadd_rn(c, d));
}

// transpose x [16384][512] -> xt [512][16384], staged in d_out (rewritten by vq_epi)
__global__ __launch_bounds__(256) void xt_kernel(const float* __restrict__ x,
                                                 float* __restrict__ xt) {
    __shared__ float t[64][65];
    const int bn = blockIdx.x;            // n tile (64 rows)
    const int bd = blockIdx.y;            // d tile (64 dims)
    const int tx = threadIdx.x & 15;      // float4 along d (or n)
    const int ty = threadIdx.x >> 4;      // 0..15
    #pragma unroll
    for (int i = 0; i < 4; ++i) {
        int nl = 16 * i + ty;
        float4 v = *(const float4*)(x + (size_t)(bn * 64 + nl) * DIM + bd * 64 + 4 * tx);
        t[4 * tx + 0][nl] = v.x;
        t[4 * tx + 1][nl] = v.y;
        t[4 * tx + 2][nl] = v.z;
        t[4 * tx + 3][nl] = v.w;
    }
    __syncthreads();
    #pragma unroll
    for (int i = 0; i < 4; ++i) {
        int dl = 16 * i + ty;
        float4 w;
        w.x = t[dl][4 * tx + 0];
        w.y = t[dl][4 * tx + 1];
        w.z = t[dl][4 * tx + 2];
        w.w = t[dl][4 * tx + 3];
        *(float4*)(xt + (size_t)(bd * 64 + dl) * N_ROWS + bn * 64 + 4 * tx) = w;
    }
}

// Wave-uniform-row GEMM: wave w owns rows rwu..rwu+15 (X via uniform/scalar
// loads from xt -- zero LDS traffic for X), lane owns 8 codes. acc[16][8]=128
// VGPRs (gfx950 VALU code hard-caps at 256 arch VGPRs -- rounds 5/6 evidence).
__global__ __launch_bounds__(THREADS, 2) void vq_main(const float* __restrict__ xt,
                                                      const float* __restrict__ emb,
                                                      const float* __restrict__ xx,
                                                      float* __restrict__ bv0,
                                                      int* __restrict__ bi0,
                                                      float* __restrict__ bv1,
                                                      int* __restrict__ bi1) {
    __shared__ float Et[2][BD * BK];      // E tile [dd][code], double-buffered (32 KB)

    const int tid  = threadIdx.x;
    const int lane = tid & 63;
    const int wv   = tid >> 6;            // 0..7
    const int wvu  = __builtin_amdgcn_readfirstlane(wv);   // provably wave-uniform
    const int rt   = blockIdx.x >> 1;     // row tile
    const int h    = blockIdx.x & 1;      // code half
    const int r0   = rt * BM;
    const int kb   = h * KHALF;
    const int rwu  = r0 + (wvu << 4);     // wave's first row (uniform)

    const float4* emb4 = (const float4*)emb;
    const float4* xt4  = (const float4*)xt;
    const int cc = tid;                   // staged code id within strip (0..511)

    float bestv[16];
    int   besti[16];
    #pragma unroll
    for (int i = 0; i < 16; ++i) { bestv[i] = 3.402823466e38f; besti[i] = 0; }

    float4 pe0, pe1;
    pe0 = emb4[(size_t)(kb + cc) * DQV + 0];
    pe1 = emb4[(size_t)(kb + cc) * DQV + 1];

    for (int kc = 0; kc < NSTRIP; ++kc) {
        const int k0 = kb + kc * BK;

        float acc[16][8];
        #pragma unroll
        for (int i = 0; i < 16; ++i)
            #pragma unroll
            for (int j = 0; j < 8; ++j) acc[i][j] = 0.0f;

        __syncthreads();   // prior strip finished all reads of buf0
        {
            Et[0][0 * BK + cc] = pe0.x; Et[0][1 * BK + cc] = pe0.y;
            Et[0][2 * BK + cc] = pe0.z; Et[0][3 * BK + cc] = pe0.w;
            Et[0][4 * BK + cc] = pe1.x; Et[0][5 * BK + cc] = pe1.y;
            Et[0][6 * BK + cc] = pe1.z; Et[0][7 * BK + cc] = pe1.w;
        }

        for (int dc = 0; dc < DCS; ++dc) {
            const int buf = dc & 1;
            __syncthreads();   // buf ready; other buf's readers done

            // prefetch next E tile (next dc, or next strip's dc=0)
            {
                int nk0, ndq;
                if (dc < DCS - 1) { nk0 = k0; ndq = 2 * (dc + 1); }
                else { nk0 = (kc < NSTRIP - 1) ? k0 + BK : kb; ndq = 0; }
                pe0 = emb4[(size_t)(nk0 + cc) * DQV + ndq];
                pe1 = emb4[(size_t)(nk0 + cc) * DQV + ndq + 1];
            }

            const int dbase = dc * BD;
            // k-sequential fp32 FMA chain per (row,code) — bit-matches BLAS GEBP
            #pragma unroll
            for (int dd = 0; dd < BD; ++dd) {
                // X: 16 wave-uniform floats from xt row (scalar-load path)
                const float4* xp4 = xt4 + (size_t)(dbase + dd) * (N_ROWS / 4) + (rwu >> 2);
                float4 xa = xp4[0], xb = xp4[1], xc = xp4[2], xd = xp4[3];
                const float* ep = &Et[buf][dd * BK + 4 * lane];
                float4 e0 = *(const float4*)(ep);
                float4 e1 = *(const float4*)(ep + 256);
                float xs[16] = {xa.x, xa.y, xa.z, xa.w, xb.x, xb.y, xb.z, xb.w,
                                xc.x, xc.y, xc.z, xc.w, xd.x, xd.y, xd.z, xd.w};
                float ev[8]  = {e0.x, e0.y, e0.z, e0.w, e1.x, e1.y, e1.z, e1.w};
                #pragma unroll
                for (int i = 0; i < 16; ++i)
                    #pragma unroll
                    for (int j = 0; j < 8; ++j)
                        acc[i][j] = __fmaf_rn(xs[i], ev[j], acc[i][j]);
            }

            // store next tile into the other buffer (its readers passed the
            // barrier at the top of this iteration)
            if (dc < DCS - 1) {
                const int nb = buf ^ 1;
                Et[nb][0 * BK + cc] = pe0.x; Et[nb][1 * BK + cc] = pe0.y;
                Et[nb][2 * BK + cc] = pe0.z; Et[nb][3 * BK + cc] = pe0.w;
                Et[nb][4 * BK + cc] = pe1.x; Et[nb][5 * BK + cc] = pe1.y;
                Et[nb][6 * BK + cc] = pe1.z; Et[nb][7 * BK + cc] = pe1.w;
            }
        }

        // strip epilogue: s = fl(xx - 2*dot); lane-local running argmin.
        // Lane codes ascend (4l..4l+3 then 256+4l..+3); strips ascend; strict <
        // keeps lowest code per fp32 ulp-bin = numpy first-min.
        #pragma unroll
        for (int i = 0; i < 16; ++i) {
            float xr_n = xx[rwu + i];
            #pragma unroll
            for (int j2 = 0; j2 < 2; ++j2) {
                #pragma unroll
                for (int t = 0; t < 4; ++t) {
                    float s = __fmaf_rn(-2.0f, acc[i][4 * j2 + t], xr_n);
                    int code = k0 + 256 * j2 + 4 * lane + t;
                    if (s < bestv[i]) { bestv[i] = s; besti[i] = code; }
                }
            }
        }
    }

    // ---- cross-lane argmin (wave shuffle butterfly, once per kernel) ----
    #pragma unroll
    for (int i = 0; i < 16; ++i) {
        float v  = bestv[i];
        int  idx = besti[i];
        #pragma unroll
        for (int off = 32; off > 0; off >>= 1) {
            float vv = __shfl_down(v, off);
            int   ii = __shfl_down(idx, off);
            if (vv < v || (vv == v && ii < idx)) { v = vv; idx = ii; }
        }
        if (lane == 0) {
            if (h == 0) { bv0[rwu + i] = v; bi0[rwu + i] = idx; }
            else        { bv1[rwu + i] = v; bi1[rwu + i] = idx; }
        }
    }
}

// merge halves + gather + straight-through + loss
__global__ __launch_bounds__(256) void vq_epi(const float* __restrict__ x,
                                              const float* __restrict__ emb,
                                              const float* __restrict__ bv0,
                                              const int* __restrict__ bi0,
                                              const float* __restrict__ bv1,
                                              const int* __restrict__ bi1,
                                              float* __restrict__ out,
                                              double* __restrict__ ws_loss,
                                              int* __restrict__ ws_maxidx) {
    __shared__ int idxRow[EPI_BM];
    const int tid = threadIdx.x;
    const int r0  = blockIdx.x * EPI_BM;
    const float4* x4   = (const float4*)x;
    const float4* emb4 = (const float4*)emb;
    float4*       out4 = (float4*)out;

    if (tid < EPI_BM) {
        int row = r0 + tid;
        float v0 = bv0[row]; int i0 = bi0[row];
        float v1 = bv1[row]; int i1 = bi1[row];
        // half0 codes all < half1 codes: tie (v1==v0) keeps i0 = numpy first-min
        int idx = (v1 < v0) ? i1 : i0;
        idxRow[tid] = idx;
        out[OUT_IDX + row] = (float)idx;
        atomicMax(ws_maxidx, idx);
    }
    __syncthreads();

    double lsum = 0.0;
    for (int i = tid; i < EPI_BM * DQV; i += 256) {
        int row = i >> 7, dq = i & 127;
        int ki  = idxRow[row];
        float4 q  = emb4[(size_t)ki * DQV + dq];
        float4 xv = x4[(size_t)(r0 + row) * DQV + dq];
        float d0 = q.x - xv.x, d1 = q.y - xv.y, d2 = q.z - xv.z, d3 = q.w - xv.w;
        lsum += (double)d0 * (double)d0 + (double)d1 * (double)d1
              + (double)d2 * (double)d2 + (double)d3 * (double)d3;
        float4 o;
        o.x = xv.x + d0; o.y = xv.y + d1; o.z = xv.z + d2; o.w = xv.w + d3;
        out4[(size_t)(r0 + row) * DQV + dq] = o;
    }
    #pragma unroll
    for (int off = 32; off > 0; off >>= 1) lsum += __shfl_down(lsum, off);
    if ((tid & 63) == 0) atomicAdd(ws_loss, lsum);
}

__global__ void vq_final(const double* __restrict__ ws_loss,
                         const int* __restrict__ ws_maxidx,
                         float* __restrict__ out) {
    if (threadIdx.x == 0) {
        double mean = *ws_loss / (double)((size_t)N_ROWS * DIM);
        out[OUT_LOSS] = (float)(1.25 * mean);   // q_latent + 0.25*e_latent
        double L   = (double)(*ws_maxidx + 1);
        double avg = 1.0 / L;
        out[OUT_PERP] = (float)exp(-avg * log(avg + 1e-10));
    }
}

extern "C" void kernel_launch(void* const* d_in, const int* in_sizes, int n_in,
                              void* d_out, int out_size, void* d_ws, size_t ws_size,
                              hipStream_t stream) {
    const float* x   = (const float*)d_in[0];
    const float* emb = (const float*)d_in[1];
    float* out = (float*)d_out;

    char* ws = (char*)d_ws;
    float*  xx        = (float*)(ws + WS_XX);
    float*  bv0       = (float*)(ws + WS_BV0);
    int*    bi0       = (int*)  (ws + WS_BI0);
    float*  bv1       = (float*)(ws + WS_BV1);
    int*    bi1       = (int*)  (ws + WS_BI1);
    double* ws_loss   = (double*)(ws + WS_LOSS);
    int*    ws_maxidx = (int*)  (ws + WS_MAXI);

    // xt lives in d_out[0 .. 8388608) -- dead space until vq_epi rewrites it
    float* xt = out;

    hipLaunchKernelGGL(init_ws, dim3(1), dim3(1), 0, stream, ws_loss, ws_maxidx);
    hipLaunchKernelGGL(xx_kernel, dim3(N_ROWS / 256), dim3(256), 0, stream,
                       (const float4*)x, xx);
    hipLaunchKernelGGL(xt_kernel, dim3(N_ROWS / 64, DIM / 64), dim3(256), 0, stream,
                       x, xt);
    hipLaunchKernelGGL(vq_main, dim3((N_ROWS / BM) * NSPLIT), dim3(THREADS), 0, stream,
                       xt, emb, xx, bv0, bi0, bv1, bi1);
    hipLaunchKernelGGL(vq_epi, dim3(N_ROWS / EPI_BM), dim3(256), 0, stream,
                       x, emb, bv0, bi0, bv1, bi1, out, ws_loss, ws_maxidx);
    hipLaunchKernelGGL(vq_final, dim3(1), dim3(64), 0, stream,
                       ws_loss, ws_maxidx, out);
}

// Round 8
// 1783.828 us; speedup vs baseline: 3.7872x; 1.0420x over previous
//
#include <hip/hip_runtime.h>
#include <math.h>

#define N_ROWS   16384
#define DIM      512
#define DQV      128          // DIM/4 float4s per row
#define K_CODES  8192
#define NSPLIT   2
#define KHALF    (K_CODES / NSPLIT)
#define BM       128          // rows per block = 16 waves x 8 rows
#define BK       512          // codes per strip
#define BD       8            // d-chunk per tile
#define DCS      (DIM / BD)   // 64 d-chunks
#define NSTRIP   (KHALF / BK) // 8 strips per half
#define THREADS  1024         // 16 waves = 4 waves/SIMD in ONE block (guaranteed co-resident)
#define EPI_BM   64

#define OUT_LOSS 8388608
#define OUT_PERP 8388609
#define OUT_IDX  8388610

// workspace layout (bytes)
#define WS_XX    0            // 16384 f32
#define WS_BV0   65536        // 16384 f32
#define WS_BI0   131072       // 16384 i32
#define WS_BV1   196608       // 16384 f32
#define WS_BI1   262144       // 16384 i32
#define WS_LOSS  327680       // double
#define WS_MAXI  327688       // int

__global__ void init_ws(double* ws_loss, int* ws_maxidx) {
    *ws_loss = 0.0;
    *ws_maxidx = 0;
}

// ---- numpy pairwise-sum emulation of xx[n] = np.sum(flat**2, axis=1) ----
__device__ __forceinline__ float p128_sq(const float4* p) {
    float4 q0 = p[0], q1 = p[1];
    float r0 = __fmul_rn(q0.x, q0.x), r1 = __fmul_rn(q0.y, q0.y);
    float r2 = __fmul_rn(q0.z, q0.z), r3 = __fmul_rn(q0.w, q0.w);
    float r4 = __fmul_rn(q1.x, q1.x), r5 = __fmul_rn(q1.y, q1.y);
    float r6 = __fmul_rn(q1.z, q1.z), r7 = __fmul_rn(q1.w, q1.w);
    #pragma unroll
    for (int t = 1; t < 16; ++t) {
        q0 = p[2 * t]; q1 = p[2 * t + 1];
        r0 = __fadd_rn(r0, __fmul_rn(q0.x, q0.x));
        r1 = __fadd_rn(r1, __fmul_rn(q0.y, q0.y));
        r2 = __fadd_rn(r2, __fmul_rn(q0.z, q0.z));
        r3 = __fadd_rn(r3, __fmul_rn(q0.w, q0.w));
        r4 = __fadd_rn(r4, __fmul_rn(q1.x, q1.x));
        r5 = __fadd_rn(r5, __fmul_rn(q1.y, q1.y));
        r6 = __fadd_rn(r6, __fmul_rn(q1.z, q1.z));
        r7 = __fadd_rn(r7, __fmul_rn(q1.w, q1.w));
    }
    return __fadd_rn(__fadd_rn(__fadd_rn(r0, r1), __fadd_rn(r2, r3)),
                     __fadd_rn(__fadd_rn(r4, r5), __fadd_rn(r6, r7)));
}

__global__ __launch_bounds__(256) void xx_kernel(const float4* __restrict__ x4,
                                                 float* __restrict__ xx) {
    int row = blockIdx.x * 256 + threadIdx.x;
    const float4* p = x4 + (size_t)row * DQV;
    float a = p128_sq(p);
    float b = p128_sq(p + 32);
    float c = p128_sq(p + 64);
    float d = p128_sq(p + 96);
    xx[row] = __fadd_rn(__fadd_rn(a, b), __fadd_rn(c, d));
}

// transpose x [16384][512] -> xt [512][16384], staged in d_out (rewritten by vq_epi)
__global__ __launch_bounds__(256) void xt_kernel(const float* __restrict__ x,
                                                 float* __restrict__ xt) {
    __shared__ float t[64][65];
    const int bn = blockIdx.x;            // n tile (64 rows)
    const int bd = blockIdx.y;            // d tile (64 dims)
    const int tx = threadIdx.x & 15;
    const int ty = threadIdx.x >> 4;
    #pragma unroll
    for (int i = 0; i < 4; ++i) {
        int nl = 16 * i + ty;
        float4 v = *(const float4*)(x + (size_t)(bn * 64 + nl) * DIM + bd * 64 + 4 * tx);
        t[4 * tx + 0][nl] = v.x;
        t[4 * tx + 1][nl] = v.y;
        t[4 * tx + 2][nl] = v.z;
        t[4 * tx + 3][nl] = v.w;
    }
    __syncthreads();
    #pragma unroll
    for (int i = 0; i < 4; ++i) {
        int dl = 16 * i + ty;
        float4 w;
        w.x = t[dl][4 * tx + 0];
        w.y = t[dl][4 * tx + 1];
        w.z = t[dl][4 * tx + 2];
        w.w = t[dl][4 * tx + 3];
        *(float4*)(xt + (size_t)(bd * 64 + dl) * N_ROWS + bn * 64 + 4 * tx) = w;
    }
}

// Wave-uniform-row GEMM, 16 waves/block = 4 waves/SIMD for latency hiding.
// Wave owns 8 rows (X via scalar loads from xt), lane owns 8 codes.
// acc[8][8]=64 VGPRs -> fits the 128-VGPR/wave budget 4 waves/SIMD requires.
__global__ __launch_bounds__(THREADS) void vq_main(const float* __restrict__ xt,
                                                   const float* __restrict__ emb,
                                                   const float* __restrict__ xx,
                                                   float* __restrict__ bv0,
                                                   int* __restrict__ bi0,
                                                   float* __restrict__ bv1,
                                                   int* __restrict__ bi1) {
    __shared__ float Et[2][BD * BK];      // E tile [dd][code], double-buffered (32 KB)

    const int tid  = threadIdx.x;
    const int lane = tid & 63;
    const int wv   = tid >> 6;            // 0..15
    const int wvu  = __builtin_amdgcn_readfirstlane(wv);
    const int rt   = blockIdx.x >> 1;     // row tile
    const int h    = blockIdx.x & 1;      // code half
    const int r0   = rt * BM;
    const int kb   = h * KHALF;
    const int rwu  = r0 + (wvu << 3);     // wave's first row (uniform, multiple of 8)

    const float4* emb4 = (const float4*)emb;
    const float4* xt4  = (const float4*)xt;
    const int cc = tid & 511;             // staged code id within strip
    const int dh = tid >> 9;              // which float4 of the 8-dim chunk (0/1)

    float bestv[8];
    int   besti[8];
    #pragma unroll
    for (int i = 0; i < 8; ++i) { bestv[i] = 3.402823466e38f; besti[i] = 0; }

    float4 pe = emb4[(size_t)(kb + cc) * DQV + dh];   // prefetch (strip 0, dc 0)

    for (int kc = 0; kc < NSTRIP; ++kc) {
        const int k0 = kb + kc * BK;

        float acc[8][8];
        #pragma unroll
        for (int i = 0; i < 8; ++i)
            #pragma unroll
            for (int j = 0; j < 8; ++j) acc[i][j] = 0.0f;

        __syncthreads();   // prior strip finished all reads of buf0
        {
            const int db = 4 * dh;
            Et[0][(db + 0) * BK + cc] = pe.x;
            Et[0][(db + 1) * BK + cc] = pe.y;
            Et[0][(db + 2) * BK + cc] = pe.z;
            Et[0][(db + 3) * BK + cc] = pe.w;
        }

        for (int dc = 0; dc < DCS; ++dc) {
            const int buf = dc & 1;
            __syncthreads();   // buf ready; other buf's readers done

            // prefetch next E tile (next dc, or next strip's dc=0)
            {
                int nk0, ndq;
                if (dc < DCS - 1) { nk0 = k0; ndq = 2 * (dc + 1) + dh; }
                else { nk0 = (kc < NSTRIP - 1) ? k0 + BK : kb; ndq = dh; }
                pe = emb4[(size_t)(nk0 + cc) * DQV + ndq];
            }

            const int dbase = dc * BD;
            // k-sequential fp32 FMA chain per (row,code) — bit-matches BLAS GEBP
            #pragma unroll
            for (int dd = 0; dd < BD; ++dd) {
                // X: 8 wave-uniform floats (scalar-load path)
                const float4* xp4 = xt4 + (size_t)(dbase + dd) * (N_ROWS / 4) + (rwu >> 2);
                float4 xa = xp4[0], xb = xp4[1];
                const float* ep = &Et[buf][dd * BK + 4 * lane];
                float4 e0 = *(const float4*)(ep);
                float4 e1 = *(const float4*)(ep + 256);
                float xs[8] = {xa.x, xa.y, xa.z, xa.w, xb.x, xb.y, xb.z, xb.w};
                float ev[8] = {e0.x, e0.y, e0.z, e0.w, e1.x, e1.y, e1.z, e1.w};
                #pragma unroll
                for (int i = 0; i < 8; ++i)
                    #pragma unroll
                    for (int j = 0; j < 8; ++j)
                        acc[i][j] = __fmaf_rn(xs[i], ev[j], acc[i][j]);
            }

            // store next tile into the other buffer (its readers passed the
            // barrier at the top of this iteration)
            if (dc < DCS - 1) {
                const int nb = buf ^ 1;
                const int db = 4 * dh;
                Et[nb][(db + 0) * BK + cc] = pe.x;
                Et[nb][(db + 1) * BK + cc] = pe.y;
                Et[nb][(db + 2) * BK + cc] = pe.z;
                Et[nb][(db + 3) * BK + cc] = pe.w;
            }
        }

        // strip epilogue: s = fl(xx - 2*dot); lane-local running argmin.
        // Lane codes ascend (4l..4l+3 then 256+4l..+3); strips ascend; strict <
        // keeps lowest code per fp32 ulp-bin = numpy first-min.
        #pragma unroll
        for (int i = 0; i < 8; ++i) {
            float xr_n = xx[rwu + i];
            #pragma unroll
            for (int j2 = 0; j2 < 2; ++j2) {
                #pragma unroll
                for (int t = 0; t < 4; ++t) {
                    float s = __fmaf_rn(-2.0f, acc[i][4 * j2 + t], xr_n);
                    int code = k0 + 256 * j2 + 4 * lane + t;
                    if (s < bestv[i]) { bestv[i] = s; besti[i] = code; }
                }
            }
        }
    }

    // ---- cross-lane argmin (wave shuffle butterfly, once per kernel) ----
    #pragma unroll
    for (int i = 0; i < 8; ++i) {
        float v  = bestv[i];
        int  idx = besti[i];
        #pragma unroll
        for (int off = 32; off > 0; off >>= 1) {
            float vv = __shfl_down(v, off);
            int   ii = __shfl_down(idx, off);
            if (vv < v || (vv == v && ii < idx)) { v = vv; idx = ii; }
        }
        if (lane == 0) {
            if (h == 0) { bv0[rwu + i] = v; bi0[rwu + i] = idx; }
            else        { bv1[rwu + i] = v; bi1[rwu + i] = idx; }
        }
    }
}

// merge halves + gather + straight-through + loss
__global__ __launch_bounds__(256) void vq_epi(const float* __restrict__ x,
                                              const float* __restrict__ emb,
                                              const float* __restrict__ bv0,
                                              const int* __restrict__ bi0,
                                              const float* __restrict__ bv1,
                                              const int* __restrict__ bi1,
                                              float* __restrict__ out,
                                              double* __restrict__ ws_loss,
                                              int* __restrict__ ws_maxidx) {
    __shared__ int idxRow[EPI_BM];
    const int tid = threadIdx.x;
    const int r0  = blockIdx.x * EPI_BM;
    const float4* x4   = (const float4*)x;
    const float4* emb4 = (const float4*)emb;
    float4*       out4 = (float4*)out;

    if (tid < EPI_BM) {
        int row = r0 + tid;
        float v0 = bv0[row]; int i0 = bi0[row];
        float v1 = bv1[row]; int i1 = bi1[row];
        // half0 codes all < half1 codes: tie (v1==v0) keeps i0 = numpy first-min
        int idx = (v1 < v0) ? i1 : i0;
        idxRow[tid] = idx;
        out[OUT_IDX + row] = (float)idx;
        atomicMax(ws_maxidx, idx);
    }
    __syncthreads();

    double lsum = 0.0;
    for (int i = tid; i < EPI_BM * DQV; i += 256) {
        int row = i >> 7, dq = i & 127;
        int ki  = idxRow[row];
        float4 q  = emb4[(size_t)ki * DQV + dq];
        float4 xv = x4[(size_t)(r0 + row) * DQV + dq];
        float d0 = q.x - xv.x, d1 = q.y - xv.y, d2 = q.z - xv.z, d3 = q.w - xv.w;
        lsum += (double)d0 * (double)d0 + (double)d1 * (double)d1
              + (double)d2 * (double)d2 + (double)d3 * (double)d3;
        float4 o;
        o.x = xv.x + d0; o.y = xv.y + d1; o.z = xv.z + d2; o.w = xv.w + d3;
        out4[(size_t)(r0 + row) * DQV + dq] = o;
    }
    #pragma unroll
    for (int off = 32; off > 0; off >>= 1) lsum += __shfl_down(lsum, off);
    if ((tid & 63) == 0) atomicAdd(ws_loss, lsum);
}

__global__ void vq_final(const double* __restrict__ ws_loss,
                         const int* __restrict__ ws_maxidx,
                         float* __restrict__ out) {
    if (threadIdx.x == 0) {
        double mean = *ws_loss / (double)((size_t)N_ROWS * DIM);
        out[OUT_LOSS] = (float)(1.25 * mean);   // q_latent + 0.25*e_latent
        double L   = (double)(*ws_maxidx + 1);
        double avg = 1.0 / L;
        out[OUT_PERP] = (float)exp(-avg * log(avg + 1e-10));
    }
}

extern "C" void kernel_launch(void* const* d_in, const int* in_sizes, int n_in,
                              void* d_out, int out_size, void* d_ws, size_t ws_size,
                              hipStream_t stream) {
    const float* x   = (const float*)d_in[0];
    const float* emb = (const float*)d_in[1];
    float* out = (float*)d_out;

    char* ws = (char*)d_ws;
    float*  xx        = (float*)(ws + WS_XX);
    float*  bv0       = (float*)(ws + WS_BV0);
    int*    bi0       = (int*)  (ws + WS_BI0);
    float*  bv1       = (float*)(ws + WS_BV1);
    int*    bi1       = (int*)  (ws + WS_BI1);
    double* ws_loss   = (double*)(ws + WS_LOSS);
    int*    ws_maxidx = (int*)  (ws + WS_MAXI);

    // xt lives in d_out[0 .. 8388608) -- dead space until vq_epi rewrites it
    float* xt = out;

    hipLaunchKernelGGL(init_ws, dim3(1), dim3(1), 0, stream, ws_loss, ws_maxidx);
    hipLaunchKernelGGL(xx_kernel, dim3(N_ROWS / 256), dim3(256), 0, stream,
                       (const float4*)x, xx);
    hipLaunchKernelGGL(xt_kernel, dim3(N_ROWS / 64, DIM / 64), dim3(256), 0, stream,
                       x, xt);
    hipLaunchKernelGGL(vq_main, dim3((N_ROWS / BM) * NSPLIT), dim3(THREADS), 0, stream,
                       xt, emb, xx, bv0, bi0, bv1, bi1);
    hipLaunchKernelGGL(vq_epi, dim3(N_ROWS / EPI_BM), dim3(256), 0, stream,
                       x, emb, bv0, bi0, bv1, bi1, out, ws_loss, ws_maxidx);
    hipLaunchKernelGGL(vq_final, dim3(1), dim3(64), 0, stream,
                       ws_loss, ws_maxidx, out);
}